// Round 4
// baseline (598.282 us; speedup 1.0000x reference)
//
#include <hip/hip_runtime.h>
#include <cstddef>

// ---------------- constants ----------------
#define NXI   512
#define LL    128
#define NST   128
#define NU    64
#define BATCH 32768
#define TW    1152          // 2n + l
#define EPSC  0.001f
#define KC    768           // concat K: xi(512) | eps(128) | w(128)
#define NC    576           // concat N: xi'(512) | u(64)
#define NCP   640           // NC padded to 128

typedef unsigned short u16;
typedef __attribute__((ext_vector_type(8))) short   short8;
typedef __attribute__((ext_vector_type(4))) short   short4v;
typedef __attribute__((ext_vector_type(4))) float   f32x4;

__device__ __forceinline__ u16 f2bf(float f) {
    unsigned u = __float_as_uint(f);
    u += 0x7FFFu + ((u >> 16) & 1u);   // RNE
    return (u16)(u >> 16);
}

// ---------------- transpose+convert X -> XT (bf16), XT[i][k] = X[k][i] ----------------
__global__ __launch_bounds__(256) void k_transpose(const float* __restrict__ X, u16* __restrict__ XT) {
    __shared__ float t[32][33];
    int tx = threadIdx.x & 31, ty = threadIdx.x >> 5;
    int bx = blockIdx.x, by = blockIdx.y;
    #pragma unroll
    for (int q = 0; q < 4; q++) {
        int r = ty + q * 8;
        t[r][tx] = X[(size_t)(by * 32 + r) * TW + bx * 32 + tx];
    }
    __syncthreads();
    #pragma unroll
    for (int q = 0; q < 4; q++) {
        int r = ty + q * 8;
        XT[(size_t)(bx * 32 + r) * TW + by * 32 + tx] = f2bf(t[tx][r]);
    }
}

// ---------------- build Ac = [bf16(xi) | (eps gap) | bf16(w)] (BATCH x 768) ----------------
__global__ __launch_bounds__(256) void k_build_Ac(const float* __restrict__ xi, const float* __restrict__ w,
                                                  u16* __restrict__ Ac) {
    size_t t = (size_t)blockIdx.x * 256 + threadIdx.x;   // chunk id, 8 elems each
    int b = (int)(t / 80), ch = (int)(t % 80);
    const float* src;
    int col;
    if (ch < 64) { src = xi + (size_t)b * NXI + ch * 8;        col = ch * 8; }
    else         { src = w  + (size_t)b * NST + (ch - 64) * 8; col = 640 + (ch - 64) * 8; }
    f32x4 a = ((const f32x4*)src)[0], c = ((const f32x4*)src)[1];
    short8 o;
    o[0]=(short)f2bf(a[0]); o[1]=(short)f2bf(a[1]); o[2]=(short)f2bf(a[2]); o[3]=(short)f2bf(a[3]);
    o[4]=(short)f2bf(c[0]); o[5]=(short)f2bf(c[1]); o[6]=(short)f2bf(c[2]); o[7]=(short)f2bf(c[3]);
    *(short8*)(Ac + (size_t)b * KC + col) = o;
}

// ---------------- m97-style bf16 MFMA GEMM: C = A @ W^T (TAG only distinguishes profile names) ----
template<int TAG>
__global__ __launch_bounds__(256) void k_gemm2(const u16* __restrict__ A, int lda,
                                               const u16* __restrict__ W, int ldw,
                                               float* __restrict__ C0, int ldc0, int nsplit,
                                               float* __restrict__ C1, int ldc1,
                                               int K, int nbx, int ntrue, int swz) {
    __shared__ __align__(16) u16 As[128 * 32];
    __shared__ __align__(16) u16 Bs[128 * 32];
    int id = blockIdx.x;
    int bx, by;
    if (swz) {
        int j = id >> 3;
        int per = (int)(gridDim.x >> 3) / nbx;     // M-bands per XCD (requires nby%8==0)
        by = (id & 7) * per + j / nbx;
        bx = j - (j / nbx) * nbx;
    } else {
        by = id / nbx;
        bx = id - by * nbx;
    }
    const int tid = threadIdx.x;
    const int wave = tid >> 6, lane = tid & 63, quad = lane >> 4, l16 = lane & 15;
    const int bm0 = by * 128, bn0 = bx * 128;
    const int srow = tid >> 2, sch = (tid & 3) * 8;
    const u16* ga0 = A + (size_t)(bm0 + srow) * lda + sch;
    const u16* ga1 = ga0 + (size_t)64 * lda;
    const u16* gb0 = W + (size_t)(bn0 + srow) * ldw + sch;
    const u16* gb1 = gb0 + (size_t)64 * ldw;
    u16* la = As + wave * 512;     // wave-uniform LDS dest (lane-ordered, contiguous)
    u16* lb = Bs + wave * 512;
    const int mb = (wave >> 1) * 64, nb = (wave & 1) * 64;

    f32x4 acc[4][4];
    #pragma unroll
    for (int i = 0; i < 4; i++)
        #pragma unroll
        for (int j = 0; j < 4; j++) acc[i][j] = (f32x4){0.f, 0.f, 0.f, 0.f};

    for (int kt = 0; kt < K; kt += 32) {
        __syncthreads();
        __builtin_amdgcn_global_load_lds((void*)(ga0 + kt), (void*)la,          16, 0, 0);
        __builtin_amdgcn_global_load_lds((void*)(ga1 + kt), (void*)(la + 2048), 16, 0, 0);
        __builtin_amdgcn_global_load_lds((void*)(gb0 + kt), (void*)lb,          16, 0, 0);
        __builtin_amdgcn_global_load_lds((void*)(gb1 + kt), (void*)(lb + 2048), 16, 0, 0);
        __syncthreads();
        short8 af[4], bf[4];
        #pragma unroll
        for (int mt = 0; mt < 4; mt++) af[mt] = *(const short8*)&As[(mb + mt * 16 + l16) * 32 + quad * 8];
        #pragma unroll
        for (int nt = 0; nt < 4; nt++) bf[nt] = *(const short8*)&Bs[(nb + nt * 16 + l16) * 32 + quad * 8];
        #pragma unroll
        for (int mt = 0; mt < 4; mt++)
            #pragma unroll
            for (int nt = 0; nt < 4; nt++)
                acc[mt][nt] = __builtin_amdgcn_mfma_f32_16x16x32_bf16(af[mt], bf[nt], acc[mt][nt], 0, 0, 0);
    }
    // epilogue: per 16x16 tile, D[row=quad*4+r][col=l16] (m89-verified layout)
    #pragma unroll
    for (int mt = 0; mt < 4; mt++)
        #pragma unroll
        for (int nt = 0; nt < 4; nt++)
            #pragma unroll
            for (int r = 0; r < 4; r++) {
                int row = bm0 + mb + mt * 16 + quad * 4 + r;
                int col = bn0 + nb + nt * 16 + l16;
                if (col < ntrue) {
                    float v = acc[mt][nt][r];
                    if (col < nsplit) C0[(size_t)row * ldc0 + col] = v;
                    else              C1[(size_t)row * ldc1 + (col - nsplit)] = v;
                }
            }
}

// ---------------- derive params from H, build GJ-augmented [E | Fm B1 B2], D11, rlam, W1 ----------------
__global__ __launch_bounds__(256) void k_derive(const float* __restrict__ Hm, const float* __restrict__ Y,
                                                const float* __restrict__ B2, const float* __restrict__ D12,
                                                float* __restrict__ Agj, float* __restrict__ D11,
                                                float* __restrict__ rlam, u16* __restrict__ W1) {
    int idx = blockIdx.x * 256 + threadIdx.x;
    const int n0 = 512 * 1280, n1 = 128 * 128, n2 = 128, n3 = 128 * KC;
    if (idx < n0) {
        int i = idx / 1280, j = idx % 1280;
        float val;
        if (j < 512) {
            val = 0.5f * (Hm[(size_t)i * TW + j] + Hm[(size_t)(640 + i) * TW + 640 + j]
                          + Y[(size_t)i * 512 + j] - Y[(size_t)j * 512 + i]);
            if (i == j) val += EPSC;
        } else if (j < 1024) {
            val = Hm[(size_t)(640 + i) * TW + (j - 512)];           // Fm = H31
        } else if (j < 1152) {
            val = Hm[(size_t)(640 + i) * TW + 512 + (j - 1024)];    // B1 = H32
        } else {
            val = B2[(size_t)i * NST + (j - 1152)];
        }
        Agj[idx] = val;
        return;
    }
    idx -= n0;
    if (idx < n1) {
        int i = idx >> 7, j = idx & 127;
        D11[idx] = (j < i) ? -Hm[(size_t)(512 + i) * TW + 512 + j] : 0.f;  // -tril(H22,-1)
        return;
    }
    idx -= n1;
    if (idx < n2) {
        rlam[idx] = 2.0f / (Hm[(size_t)(512 + idx) * TW + 512 + idx] + EPSC);  // 1/(0.5*diag(H22))
        return;
    }
    idx -= n2;
    if (idx < n3) {
        int i = idx / KC, c = idx % KC;
        float v;
        if (c < 512)      v = -Hm[(size_t)(512 + i) * TW + c];      // C1 = -H21
        else if (c < 640) v = 0.f;                                  // eps slot unused for pre
        else              v = D12[(size_t)i * NST + (c - 640)];
        W1[(size_t)i * KC + c] = f2bf(v);
    }
}

// ---------------- in-wave 16x16 Jordan inverse ----------------
// lane = (colgroup<<4) | row ; a[4] = A[row][4cg..4cg+3] in ; b[4] = inv rows out
__device__ __forceinline__ void inv16_inwave(float a[4], float b[4], int lane) {
    const int row = lane & 15;
    const int cg  = lane >> 4;
    #pragma unroll
    for (int j = 0; j < 4; j++) b[j] = (cg * 4 + j == row) ? 1.f : 0.f;
    #pragma unroll
    for (int k = 0; k < 16; k++) {
        const int kcg = k >> 2, kr = k & 3;
        float pa[4], pb[4];
        int psrc = (lane & 48) + k;                  // pivot row k, my colgroup
        #pragma unroll
        for (int j = 0; j < 4; j++) {
            pa[j] = __shfl(a[j], psrc, 64);
            pb[j] = __shfl(b[j], psrc, 64);
        }
        float pivd = __shfl(a[kr], (kcg << 4) + k,   64);   // A[k][k]
        float mval = __shfl(a[kr], (kcg << 4) + row, 64);   // A[row][k]
        float rp = 1.0f / pivd;
        float m = (row == k) ? 0.f : mval * rp;
        float s = (row == k) ? rp  : 1.f;
        #pragma unroll
        for (int j = 0; j < 4; j++) {
            a[j] = s * fmaf(-m, pa[j], a[j]);
            b[j] = s * fmaf(-m, pb[j], b[j]);
        }
    }
}

// ---------------- 64x64 inverse via 16-blocked Jordan (deferred pivot scaling) ----------------
// Aq: input matrix (LDS 64x68, destroyed). Bq: 64x68 workspace. S16: 16x68. invd: 4*256 floats.
// ~14 barriers instead of 128. Writes invOut (global, row-major 64).
__device__ void invert64_fast(float* Aq, float* Bq, float* S16, float* invd,
                              float* __restrict__ invOut, int tid) {
    const int lane = tid & 63, wave = tid >> 6;
    {   // Bq = I
        int r0 = tid >> 2, c0 = (tid & 3) * 16;
        #pragma unroll
        for (int q = 0; q < 16; q++) Bq[r0 * 68 + c0 + q] = (c0 + q == r0) ? 1.f : 0.f;
    }
    __syncthreads();
    #pragma unroll
    for (int p = 0; p < 4; p++) {
        const int awid = 48 - 16 * p;   // remaining A-side trailing width (B-side = 64-awid)
        {   // inverse of current diag 16-block, in-wave (redundant per wave; wave 0 stores)
            int row = lane & 15, cg = lane >> 4;
            float a[4], b[4];
            f32x4 av = *(f32x4*)&Aq[(p * 16 + row) * 68 + p * 16 + cg * 4];
            a[0] = av[0]; a[1] = av[1]; a[2] = av[2]; a[3] = av[3];
            inv16_inwave(a, b, lane);
            if (wave == 0) {
                #pragma unroll
                for (int j = 0; j < 4; j++) invd[p * 256 + row * 16 + cg * 4 + j] = b[j];
            }
        }
        __syncthreads();
        {   // S16 = invd_p @ P ; P col c: c<awid -> Aq col 16(p+1)+c ; else Bq col c-awid
            int sr = tid & 15, sc = (tid >> 4) * 4;
            float acc[4] = {0.f, 0.f, 0.f, 0.f};
            #pragma unroll
            for (int j = 0; j < 16; j++) {
                float iv = invd[p * 256 + sr * 16 + j];
                #pragma unroll
                for (int cc = 0; cc < 4; cc++) {
                    int c = sc + cc;
                    float pv = (c < awid) ? Aq[(16 * p + j) * 68 + 16 * (p + 1) + c]
                                          : Bq[(16 * p + j) * 68 + (c - awid)];
                    acc[cc] = fmaf(iv, pv, acc[cc]);
                }
            }
            #pragma unroll
            for (int cc = 0; cc < 4; cc++) S16[sr * 68 + sc + cc] = acc[cc];
        }
        __syncthreads();
        {   // rank-16 trailing update of the 48 non-pivot rows
            int ty = tid >> 4, tx = tid & 15;
            f32x4 sv[16];
            #pragma unroll
            for (int j = 0; j < 16; j++) sv[j] = *(f32x4*)&S16[j * 68 + tx * 4];
            #pragma unroll
            for (int rr = 0; rr < 3; rr++) {
                int ri = rr * 16 + ty;
                int row = ri + (ri >= 16 * p ? 16 : 0);
                f32x4 mv[4];
                #pragma unroll
                for (int q = 0; q < 4; q++) mv[q] = *(f32x4*)&Aq[row * 68 + 16 * p + q * 4];
                int c = tx * 4;                      // awid%16==0 -> all 4 cols same side
                float* dst = (c < awid) ? &Aq[row * 68 + 16 * (p + 1) + c]
                                        : &Bq[row * 68 + (c - awid)];
                f32x4 cur = *(f32x4*)dst;
                #pragma unroll
                for (int j = 0; j < 16; j++) {
                    float m = mv[j >> 2][j & 3];
                    cur[0] = fmaf(-m, sv[j][0], cur[0]);
                    cur[1] = fmaf(-m, sv[j][1], cur[1]);
                    cur[2] = fmaf(-m, sv[j][2], cur[2]);
                    cur[3] = fmaf(-m, sv[j][3], cur[3]);
                }
                *(f32x4*)dst = cur;
            }
        }
        __syncthreads();
    }
    {   // finalize: invOut rows of band p = invd_p @ Bq[band p, :]
        int row = tid >> 2, p = row >> 4, r = row & 15, cb = (tid & 3) * 16;
        float acc[16];
        #pragma unroll
        for (int cc = 0; cc < 16; cc++) acc[cc] = 0.f;
        #pragma unroll
        for (int j = 0; j < 16; j++) {
            float iv = invd[p * 256 + r * 16 + j];
            #pragma unroll
            for (int cc = 0; cc < 16; cc++)
                acc[cc] = fmaf(iv, Bq[(p * 16 + j) * 68 + cb + cc], acc[cc]);
        }
        #pragma unroll
        for (int q = 0; q < 4; q++)
            *(f32x4*)&invOut[row * 64 + cb + q * 4] =
                (f32x4){acc[q * 4], acc[q * 4 + 1], acc[q * 4 + 2], acc[q * 4 + 3]};
    }
}

__global__ __launch_bounds__(256) void k_diaginv0(const float* __restrict__ Agj, float* __restrict__ invD) {
    __shared__ __align__(16) float Aq[64 * 68];
    __shared__ __align__(16) float Bq[64 * 68];
    __shared__ __align__(16) float S16[16 * 68];
    __shared__ __align__(16) float invd[1024];
    int tid = threadIdx.x, r = tid >> 2, c4 = tid & 3;
    #pragma unroll
    for (int q = 0; q < 4; q++)
        *(f32x4*)&Aq[r * 68 + c4 * 16 + q * 4] = *(const f32x4*)(Agj + (size_t)r * 1280 + c4 * 16 + q * 4);
    __syncthreads();
    invert64_fast(Aq, Bq, S16, invd, invD, tid);
}

// ---------------- GJ eliminate step k (deferred pivot-row scaling) ----------------
// grid: x = 19-k (cb = k+1+bx), y = 7 (rb = all row blocks != k). Block (0,k) also
// inverts the next diag tile via invert64_fast (reusing Ms/Ss as workspace).
__global__ __launch_bounds__(256) void k_elim(float* __restrict__ Agj, float* __restrict__ invD, int k) {
    __shared__ __align__(16) float invDs[64 * 68];
    __shared__ __align__(16) float Ps[64 * 68];
    __shared__ __align__(16) float Ss[64 * 68];
    __shared__ __align__(16) float Ms[64 * 68];
    int tid = threadIdx.x;
    int by = blockIdx.y, bx = blockIdx.x;
    int rb = by + (by >= k ? 1 : 0);
    int cb = k + 1 + bx;
    int lr = tid >> 2, lc = tid & 3;
    #pragma unroll
    for (int q = 0; q < 4; q++) {
        *(f32x4*)&invDs[lr * 68 + lc * 16 + q * 4] = *(const f32x4*)(invD + (size_t)k * 4096 + lr * 64 + lc * 16 + q * 4);
        *(f32x4*)&Ps[lr * 68 + lc * 16 + q * 4]    = *(const f32x4*)(Agj + (size_t)(k * 64 + lr) * 1280 + cb * 64 + lc * 16 + q * 4);
        *(f32x4*)&Ms[lr * 68 + lc * 16 + q * 4]    = *(const f32x4*)(Agj + (size_t)(rb * 64 + lr) * 1280 + k * 64 + lc * 16 + q * 4);
    }
    __syncthreads();
    int ty = tid >> 4, tx = tid & 15;
    // S = invD_k @ P  (scaled pivot row tile, computed redundantly per block)
    f32x4 s[4];
    #pragma unroll
    for (int ri = 0; ri < 4; ri++) s[ri] = (f32x4){0.f, 0.f, 0.f, 0.f};
    for (int kk = 0; kk < 64; kk++) {
        f32x4 pv = *(f32x4*)&Ps[kk * 68 + tx * 4];
        #pragma unroll
        for (int ri = 0; ri < 4; ri++) s[ri] += pv * invDs[(ty * 4 + ri) * 68 + kk];
    }
    #pragma unroll
    for (int ri = 0; ri < 4; ri++) *(f32x4*)&Ss[(ty * 4 + ri) * 68 + tx * 4] = s[ri];
    __syncthreads();
    // C -= M @ S
    f32x4 accv[4];
    #pragma unroll
    for (int ri = 0; ri < 4; ri++)
        accv[ri] = *(const f32x4*)(Agj + (size_t)(rb * 64 + ty * 4 + ri) * 1280 + cb * 64 + tx * 4);
    for (int kk = 0; kk < 64; kk++) {
        f32x4 sv = *(f32x4*)&Ss[kk * 68 + tx * 4];
        #pragma unroll
        for (int ri = 0; ri < 4; ri++) accv[ri] -= sv * Ms[(ty * 4 + ri) * 68 + kk];
    }
    #pragma unroll
    for (int ri = 0; ri < 4; ri++)
        *(f32x4*)(Agj + (size_t)(rb * 64 + ty * 4 + ri) * 1280 + cb * 64 + tx * 4) = accv[ri];
    // fused: invert the next pivot diagonal tile while the rest of the GPU runs other tiles
    if (k < 7 && bx == 0 && by == k) {
        __syncthreads();
        #pragma unroll
        for (int ri = 0; ri < 4; ri++) *(f32x4*)&Ps[(ty * 4 + ri) * 68 + tx * 4] = accv[ri];
        invert64_fast(Ps, Ms, Ss, &Ss[20 * 68], invD + (size_t)(k + 1) * 4096, tid);
    }
}

// ---------------- finalize: Wc rows 0..511 = invD_k @ Agj[pivot rows, 512:1280] (bf16);
// rows 512..575 from C2|D21|D22; rows 576..639 zero padding ----------------
__global__ __launch_bounds__(256) void k_finalize(const float* __restrict__ Agj, const float* __restrict__ invD,
                                                  const float* __restrict__ C2, const float* __restrict__ D21,
                                                  const float* __restrict__ D22, u16* __restrict__ Wc) {
    __shared__ __align__(16) float invDs[64 * 68];
    __shared__ __align__(16) float Ps[64 * 68];
    int tid = threadIdx.x, bx = blockIdx.x, by = blockIdx.y;
    int ty = tid >> 4, tx = tid & 15;
    if (by >= 8) {
        #pragma unroll
        for (int ri = 0; ri < 4; ri++) {
            int q = ty * 4 + ri;
            int row = 512 + (by - 8) * 64 + q;
            int cbase = bx * 64 + tx * 4;
            short4v o;
            if (by == 8) {
                f32x4 v;
                if (cbase < 512)      v = *(const f32x4*)(C2 + (size_t)q * 512 + cbase);
                else if (cbase < 640) v = *(const f32x4*)(D21 + (size_t)q * NST + (cbase - 512));
                else                  v = *(const f32x4*)(D22 + (size_t)q * NST + (cbase - 640));
                o[0]=(short)f2bf(v[0]); o[1]=(short)f2bf(v[1]); o[2]=(short)f2bf(v[2]); o[3]=(short)f2bf(v[3]);
            } else {
                o[0]=0; o[1]=0; o[2]=0; o[3]=0;
            }
            *(short4v*)(Wc + (size_t)row * KC + cbase) = o;
        }
        return;
    }
    int lr = tid >> 2, lc = tid & 3;
    #pragma unroll
    for (int q = 0; q < 4; q++) {
        *(f32x4*)&invDs[lr * 68 + lc * 16 + q * 4] = *(const f32x4*)(invD + (size_t)by * 4096 + lr * 64 + lc * 16 + q * 4);
        *(f32x4*)&Ps[lr * 68 + lc * 16 + q * 4]    = *(const f32x4*)(Agj + (size_t)(by * 64 + lr) * 1280 + 512 + bx * 64 + lc * 16 + q * 4);
    }
    __syncthreads();
    f32x4 s[4];
    #pragma unroll
    for (int ri = 0; ri < 4; ri++) s[ri] = (f32x4){0.f, 0.f, 0.f, 0.f};
    for (int kk = 0; kk < 64; kk++) {
        f32x4 pv = *(f32x4*)&Ps[kk * 68 + tx * 4];
        #pragma unroll
        for (int ri = 0; ri < 4; ri++) s[ri] += pv * invDs[(ty * 4 + ri) * 68 + kk];
    }
    #pragma unroll
    for (int ri = 0; ri < 4; ri++) {
        short4v o; o[0]=(short)f2bf(s[ri][0]); o[1]=(short)f2bf(s[ri][1]); o[2]=(short)f2bf(s[ri][2]); o[3]=(short)f2bf(s[ri][3]);
        *(short4v*)(Wc + (size_t)(by * 64 + ty * 4 + ri) * KC + bx * 64 + tx * 4) = o;
    }
}

// ---------------- fused pre-GEMM (pre = Ac @ W1^T, kept in LDS) + tanh scan ----------------
// BM=128 covers all 128 scan columns -> each block computes its 128x128 pre tile into LDS,
// runs the blocked right-looking tanh recurrence, writes eps (bf16) into Ac cols 512:640.
// K-loop skips the zero eps-columns of W1 (20 iters instead of 24).
__global__ __launch_bounds__(256) void k_pre_scan(u16* __restrict__ Ac, const u16* __restrict__ W1,
                                                  const float* __restrict__ D11, const float* __restrict__ rlam) {
    __shared__ __align__(16) u16 As[128 * 32];
    __shared__ __align__(16) u16 Bs[128 * 32];
    __shared__ __align__(16) float preS[128 * 132];
    __shared__ __align__(16) float D11s[128 * 132];
    const int tid = threadIdx.x;
    {   // stage D11 (fp32) into padded LDS: 64 floats per thread
        int r = tid >> 1, c = (tid & 1) * 64;
        const f32x4* src = (const f32x4*)(D11 + (size_t)r * 128 + c);
        f32x4* dst = (f32x4*)&D11s[r * 132 + c];
        #pragma unroll
        for (int q = 0; q < 16; q++) dst[q] = src[q];
    }
    const int wave = tid >> 6, lane = tid & 63, quad = lane >> 4, l16 = lane & 15;
    const int bm0 = blockIdx.x * 128;
    const int srow = tid >> 2, sch = (tid & 3) * 8;
    const u16* ga0 = Ac + (size_t)(bm0 + srow) * KC + sch;
    const u16* ga1 = ga0 + (size_t)64 * KC;
    const u16* gb0 = W1 + (size_t)srow * KC + sch;
    const u16* gb1 = gb0 + (size_t)64 * KC;
    u16* la = As + wave * 512;
    u16* lb = Bs + wave * 512;
    const int mb = (wave >> 1) * 64, nb = (wave & 1) * 64;

    f32x4 acc[4][4];
    #pragma unroll
    for (int i = 0; i < 4; i++)
        #pragma unroll
        for (int j = 0; j < 4; j++) acc[i][j] = (f32x4){0.f, 0.f, 0.f, 0.f};

    for (int i = 0; i < 20; i++) {
        int kt = (i < 16) ? i * 32 : 640 + (i - 16) * 32;   // skip eps cols [512,640)
        __syncthreads();
        __builtin_amdgcn_global_load_lds((void*)(ga0 + kt), (void*)la,          16, 0, 0);
        __builtin_amdgcn_global_load_lds((void*)(ga1 + kt), (void*)(la + 2048), 16, 0, 0);
        __builtin_amdgcn_global_load_lds((void*)(gb0 + kt), (void*)lb,          16, 0, 0);
        __builtin_amdgcn_global_load_lds((void*)(gb1 + kt), (void*)(lb + 2048), 16, 0, 0);
        __syncthreads();
        short8 af[4], bf[4];
        #pragma unroll
        for (int mt = 0; mt < 4; mt++) af[mt] = *(const short8*)&As[(mb + mt * 16 + l16) * 32 + quad * 8];
        #pragma unroll
        for (int nt = 0; nt < 4; nt++) bf[nt] = *(const short8*)&Bs[(nb + nt * 16 + l16) * 32 + quad * 8];
        #pragma unroll
        for (int mt = 0; mt < 4; mt++)
            #pragma unroll
            for (int nt = 0; nt < 4; nt++)
                acc[mt][nt] = __builtin_amdgcn_mfma_f32_16x16x32_bf16(af[mt], bf[nt], acc[mt][nt], 0, 0, 0);
    }
    // epilogue -> preS (LDS), C-layout row=quad*4+r, col=l16
    #pragma unroll
    for (int mt = 0; mt < 4; mt++)
        #pragma unroll
        for (int nt = 0; nt < 4; nt++)
            #pragma unroll
            for (int r = 0; r < 4; r++)
                preS[(mb + mt * 16 + quad * 4 + r) * 132 + nb + nt * 16 + l16] = acc[mt][nt][r];
    __syncthreads();

    // ---- scan phase: 16 groups x 16 lanes, each group 8 rows sequential ----
    const int lg = tid & 15, grp = tid >> 4, gbase = (tid & 63) & ~15;
    const float L2E2 = 2.885390082f; // 2*log2(e)
    float a8[8];
    #pragma unroll
    for (int b = 0; b < 8; b++) a8[b] = L2E2 * rlam[b * 16 + lg];

    for (int rr = 0; rr < 8; rr++) {
        int rloc = grp * 8 + rr;
        float corrv[8];
        #pragma unroll
        for (int b = 0; b < 8; b++) corrv[b] = preS[rloc * 132 + b * 16 + lg];
        #pragma unroll
        for (int b = 0; b < 8; b++) {
            f32x4 dblk[4];
            #pragma unroll
            for (int q = 0; q < 4; q++)
                dblk[q] = *(const f32x4*)&D11s[(b * 16 + lg) * 132 + b * 16 + q * 4];
            float v = corrv[b];
            float a = a8[b];
            float e16[16];
            float myeps = 0.f;
            #pragma unroll
            for (int t = 0; t < 16; t++) {
                float ex = __builtin_amdgcn_exp2f(a * v);
                float cand = 1.0f - 2.0f * __builtin_amdgcn_rcpf(ex + 1.0f);
                float e = __shfl(cand, gbase + t, 64);
                e16[t] = e;
                if (lg == t) myeps = e;
                v = fmaf(e, dblk[t >> 2][t & 3], v);
            }
            Ac[(size_t)(bm0 + rloc) * KC + 512 + b * 16 + lg] = f2bf(myeps);
            #pragma unroll
            for (int bb = b + 1; bb < 8; bb++) {
                f32x4 dd[4];
                #pragma unroll
                for (int q = 0; q < 4; q++)
                    dd[q] = *(const f32x4*)&D11s[(bb * 16 + lg) * 132 + b * 16 + q * 4];
                float accu = corrv[bb];
                #pragma unroll
                for (int t = 0; t < 16; t++)
                    accu = fmaf(e16[t], dd[t >> 2][t & 3], accu);
                corrv[bb] = accu;
            }
        }
    }
}

// ---------------- host ----------------
extern "C" void kernel_launch(void* const* d_in, const int* in_sizes, int n_in,
                              void* d_out, int out_size, void* d_ws, size_t ws_size,
                              hipStream_t stream) {
    const float* w_in  = (const float*)d_in[1];
    const float* xi_in = (const float*)d_in[2];
    const float* X   = (const float*)d_in[3];
    const float* Y   = (const float*)d_in[4];
    const float* B2  = (const float*)d_in[5];
    const float* C2  = (const float*)d_in[6];
    const float* D21 = (const float*)d_in[7];
    const float* D22 = (const float*)d_in[8];
    const float* D12 = (const float*)d_in[9];
    float* out_u  = (float*)d_out;                       // (BATCH,1,64)
    float* out_xi = (float*)d_out + (size_t)BATCH * NU;  // (BATCH,1,512)

    char* base = (char*)d_ws;
    size_t off = 0;
    auto carve = [&](size_t bytes) -> void* {
        void* p = base + off;
        off += (bytes + 255) & ~(size_t)255;
        return p;
    };
    u16*   XT   = (u16*)  carve((size_t)TW * TW * 2);
    u16*   Ac   = (u16*)  carve((size_t)BATCH * KC * 2);
    float* Hm   = (float*)carve((size_t)TW * TW * 4);
    float* Agj  = (float*)carve((size_t)512 * 1280 * 4);
    float* invD = (float*)carve((size_t)8 * 64 * 64 * 4);
    u16*   Wc   = (u16*)  carve((size_t)NCP * KC * 2);
    u16*   W1   = (u16*)  carve((size_t)LL * KC * 2);
    float* D11  = (float*)carve((size_t)LL * LL * 4);
    float* rlam = (float*)carve((size_t)LL * 4);
    (void)ws_size; (void)in_sizes; (void)n_in; (void)out_size;

    // setup chain
    k_transpose<<<dim3(36, 36), 256, 0, stream>>>(X, XT);
    k_build_Ac<<<BATCH * 80 / 256, 256, 0, stream>>>(xi_in, w_in, Ac);
    // H = X^T X  (bf16 MFMA; +eps*I applied in k_derive). M=N=K=1152, no swizzle (nby=9)
    k_gemm2<0><<<81, 256, 0, stream>>>(XT, TW, XT, TW, Hm, TW, 1 << 30, nullptr, 0, TW, 9, TW, 0);
    k_derive<<<(512 * 1280 + 128 * 128 + 128 + 128 * KC + 255) / 256, 256, 0, stream>>>(
        Hm, Y, B2, D12, Agj, D11, rlam, W1);
    // blocked Gauss-Jordan on [E | Fm B1 B2] with fused next-diag inversion
    k_diaginv0<<<1, 256, 0, stream>>>(Agj, invD);
    for (int k = 0; k < 8; k++)
        k_elim<<<dim3(19 - k, 7), 256, 0, stream>>>(Agj, invD, k);
    k_finalize<<<dim3(12, 10), 256, 0, stream>>>(Agj, invD, C2, D21, D22, Wc);
    // batch side: fused pre-GEMM + scan, then final fused GEMM
    k_pre_scan<<<256, 256, 0, stream>>>(Ac, W1, D11, rlam);
    k_gemm2<1><<<1280, 256, 0, stream>>>(Ac, KC, Wc, KC, out_xi, NXI, 512, out_u, NU, KC, 5, NC, 1);
}